// Round 1
// baseline (178.164 us; speedup 1.0000x reference)
//
#include <hip/hip_runtime.h>

// KeypointFlowLoss: the mask is nonzero only at the B*K scattered keypoints
// (y0 = k*(H/K) is distinct per k => no scatter collisions), so the full
// (L,B,2,H,W) sum collapses to a gather over <=1088 pixels.
//
//   loss = sum_i gamma^(L-1-i) * sum_{(b,k) masked} ((p0-dx)^2+(p1-dy)^2)
//          / max(2*count_masked, 1)

#define LL 4
#define BB 64
#define KK 17
#define HH 256
#define WW 256
#define GAMMA 0.8f

__global__ __launch_bounds__(1024) void KeypointFlowLoss_28767690949028_kernel(
    const float* __restrict__ pred,   // (L,B,2,H,W) fp32
    const int*   __restrict__ kps,    // (B,2,K,2)   int32
    float*       __restrict__ out)    // scalar
{
    const int tid = threadIdx.x;
    const float wts[LL] = {GAMMA * GAMMA * GAMMA, GAMMA * GAMMA, GAMMA, 1.0f};

    float wsse = 0.0f;  // gamma-weighted SSE (division by denom is linear, do it last)
    float cnt  = 0.0f;  // masked-position count

    for (int idx = tid; idx < BB * KK; idx += 1024) {
        const int b = idx / KK;
        const int k = idx - b * KK;
        const int* k0 = kps + ((b * 2 + 0) * KK + k) * 2;
        const int* k1 = kps + ((b * 2 + 1) * KK + k) * 2;
        const int x0 = k0[0], y0 = k0[1];
        const int x1 = k1[0], y1 = k1[1];
        const int dxi = x1 - x0, dyi = y1 - y0;
        if (dxi != 0 || dyi != 0) {          // mask = |(dx,dy)| > 0
            cnt += 1.0f;
            const float dx = (float)dxi, dy = (float)dyi;
            const size_t base = (size_t)b * (2 * HH * WW) + (size_t)y0 * WW + x0;
#pragma unroll
            for (int i = 0; i < LL; ++i) {
                const size_t o = (size_t)i * (BB * 2 * HH * WW) + base;
                const float p0 = pred[o];
                const float p1 = pred[o + HH * WW];
                const float e0 = p0 - dx, e1 = p1 - dy;
                wsse += wts[i] * (e0 * e0 + e1 * e1);
            }
        }
    }

    // wave-64 shuffle reduction
#pragma unroll
    for (int off = 32; off > 0; off >>= 1) {
        wsse += __shfl_down(wsse, off, 64);
        cnt  += __shfl_down(cnt,  off, 64);
    }

    __shared__ float s_wsse[16], s_cnt[16];
    const int wave = tid >> 6;
    const int lane = tid & 63;
    if (lane == 0) { s_wsse[wave] = wsse; s_cnt[wave] = cnt; }
    __syncthreads();

    if (wave == 0) {
        float v = (lane < 16) ? s_wsse[lane] : 0.0f;
        float c = (lane < 16) ? s_cnt[lane]  : 0.0f;
#pragma unroll
        for (int off = 8; off > 0; off >>= 1) {
            v += __shfl_down(v, off, 64);
            c += __shfl_down(c, off, 64);
        }
        if (lane == 0) {
            const float denom = fmaxf(c * 2.0f, 1.0f);
            out[0] = v / denom;   // LOSS_WEIGHT = 1.0
        }
    }
}

extern "C" void kernel_launch(void* const* d_in, const int* in_sizes, int n_in,
                              void* d_out, int out_size, void* d_ws, size_t ws_size,
                              hipStream_t stream) {
    const float* pred = (const float*)d_in[0];  // (4,64,2,256,256) fp32
    const int*   kps  = (const int*)d_in[1];    // (64,2,17,2) int32
    float*       out  = (float*)d_out;          // scalar fp32
    (void)in_sizes; (void)n_in; (void)out_size; (void)d_ws; (void)ws_size;
    KeypointFlowLoss_28767690949028_kernel<<<1, 1024, 0, stream>>>(pred, kps, out);
}